// Round 2
// baseline (750.576 us; speedup 1.0000x reference)
//
#include <hip/hip_runtime.h>
#include <hip/hip_bf16.h>
#include <math.h>

// Problem constants
#define BS   32
#define GRID_N 2704
#define A_N  3
#define CH   85
#define VDIM 1024
#define HDIM 512
#define SEL  32
#define ROWS (BS*SEL)          // 1024

// Workspace layout (float element offsets; idx stored as int at base)
// Total: 1,068,032 floats = 4,272,128 bytes. Guarded against ws_size.
#define WS_VIS   1024
#define WS_VIS2  (WS_VIS + ROWS*HDIM)        // 1024 + 524288
#define WS_LN    (WS_VIS2 + ROWS*HDIM)
#define WS_W0    (WS_LN + BS*HDIM)
#define WS_W1    (WS_W0 + ROWS)
#define WS_TOTAL_FLOATS (WS_W1 + ROWS)

// ---------------------------------------------------------------- topk (score fused) + sort
__global__ __launch_bounds__(256) void topk_kernel(const float* __restrict__ boxes,
                                                   int* __restrict__ idx_out) {
    __shared__ float sc[GRID_N];
    __shared__ int   selg[SEL];
    __shared__ float rbv[4];
    __shared__ int   rbi[4];
    int b = blockIdx.x, tid = threadIdx.x;
    // score = mean over anchors of channel 4
    for (int g = tid; g < GRID_N; g += 256) {
        const float* p = boxes + ((long)(b * GRID_N + g)) * (A_N * CH);
        sc[g] = (p[4] + p[CH + 4] + p[2 * CH + 4]) * (1.0f / 3.0f);
    }
    __syncthreads();
    for (int i = 0; i < SEL; ++i) {
        float bv = -3.4e38f; int bi = 0x7fffffff;
        for (int g = tid; g < GRID_N; g += 256) {
            float v = sc[g];
            if (v > bv || (v == bv && g < bi)) { bv = v; bi = g; }
        }
        for (int off = 32; off; off >>= 1) {
            float ov = __shfl_down(bv, off);
            int   oi = __shfl_down(bi, off);
            if (ov > bv || (ov == bv && oi < bi)) { bv = ov; bi = oi; }
        }
        int lane = tid & 63, wid = tid >> 6;
        if (lane == 0) { rbv[wid] = bv; rbi[wid] = bi; }
        __syncthreads();
        if (tid == 0) {
            float fv = rbv[0]; int fi = rbi[0];
            for (int w = 1; w < 4; ++w)
                if (rbv[w] > fv || (rbv[w] == fv && rbi[w] < fi)) { fv = rbv[w]; fi = rbi[w]; }
            selg[i] = fi;
            sc[fi] = -3.4e38f;
        }
        __syncthreads();
    }
    if (tid < SEL) {
        int my = selg[tid], rank = 0;
        for (int j = 0; j < SEL; ++j) rank += (selg[j] < my);
        idx_out[b * SEL + rank] = my;
    }
}

// ---------------------------------------------------------------- lang proj + normalize
__global__ __launch_bounds__(256) void lang_kernel(const float* __restrict__ lang,
                                                   const float* __restrict__ Wts,
                                                   const float* __restrict__ bts,
                                                   float* __restrict__ lnorm) {
    __shared__ float ll[HDIM];
    __shared__ float le[HDIM];
    __shared__ float red[4];
    __shared__ float sscale;
    int b = blockIdx.x, tid = threadIdx.x;
    ll[tid]       = lang[b * HDIM + tid];
    ll[tid + 256] = lang[b * HDIM + tid + 256];
    __syncthreads();
    for (int h = tid; h < HDIM; h += 256) {
        float acc = bts[h];
        for (int k = 0; k < HDIM; ++k) acc += ll[k] * Wts[k * HDIM + h];
        le[h] = acc;
    }
    __syncthreads();
    float s = le[tid] * le[tid] + le[tid + 256] * le[tid + 256];
    for (int off = 32; off; off >>= 1) s += __shfl_down(s, off);
    int lane = tid & 63, wid = tid >> 6;
    if (lane == 0) red[wid] = s;
    __syncthreads();
    if (tid == 0) {
        float t = red[0] + red[1] + red[2] + red[3];
        sscale = 1.0f / (sqrtf(t) + 1e-8f);
    }
    __syncthreads();
    lnorm[b * HDIM + tid]       = le[tid] * sscale;
    lnorm[b * HDIM + tid + 256] = le[tid + 256] * sscale;
}

// ---------------------------------------------------------------- GEMM1 (gather fused):
// vis[b*32+s, :] = x_feat[b, :, idx[b,s]] @ W_vs + b_vs
// grid (32 batches, 8 col-tiles), block 256. Tile 32 rows x 64 cols, K=1024 in 4 tiles of 256.
#define KT 256
__global__ __launch_bounds__(256) void gemm1_kernel(const float* __restrict__ xf,
                                                    const int* __restrict__ idx,
                                                    const float* __restrict__ W,
                                                    const float* __restrict__ bias,
                                                    float* __restrict__ out) {
    __shared__ float As[KT][34];
    int tid = threadIdx.x;
    int bx = blockIdx.x, by = blockIdx.y;   // bx = batch index
    int ct = tid & 15, rt = tid >> 4;
    int c0 = by * 64 + ct * 4;
    int r0 = bx * 32 + rt * 2;
    int lrow = tid >> 3;            // 0..31  (row within batch = SEL slot)
    int lk0  = (tid & 7) * 4;       // 0..28
    int g = idx[bx * SEL + lrow];
    const float* src = xf + (long)bx * VDIM * GRID_N + g;
    float acc[2][4] = {{0.f,0.f,0.f,0.f},{0.f,0.f,0.f,0.f}};
    for (int k0 = 0; k0 < VDIM; k0 += KT) {
        #pragma unroll
        for (int j = 0; j < 8; ++j) {
            int kk = lk0 + j * 32;
            #pragma unroll
            for (int i = 0; i < 4; ++i)
                As[kk + i][lrow] = src[(long)(k0 + kk + i) * GRID_N];
        }
        __syncthreads();
        #pragma unroll 8
        for (int k = 0; k < KT; ++k) {
            float4 w = *(const float4*)&W[(long)(k0 + k) * HDIM + c0];
            float2 a = *(const float2*)&As[k][2 * rt];
            acc[0][0] += a.x * w.x; acc[0][1] += a.x * w.y;
            acc[0][2] += a.x * w.z; acc[0][3] += a.x * w.w;
            acc[1][0] += a.y * w.x; acc[1][1] += a.y * w.y;
            acc[1][2] += a.y * w.z; acc[1][3] += a.y * w.w;
        }
        __syncthreads();
    }
    float4 bv = *(const float4*)&bias[c0];
    #pragma unroll
    for (int i = 0; i < 2; ++i) {
        float4 o;
        o.x = acc[i][0] + bv.x; o.y = acc[i][1] + bv.y;
        o.z = acc[i][2] + bv.z; o.w = acc[i][3] + bv.w;
        *(float4*)&out[(long)(r0 + i) * HDIM + c0] = o;
    }
}

// ---------------------------------------------------------------- logits / log-softmax weights
__global__ __launch_bounds__(256) void logits_kernel(const float* __restrict__ vis,
                                                     const float* __restrict__ tag,
                                                     const float* __restrict__ pos,
                                                     const float* __restrict__ Wsoft,
                                                     const float* __restrict__ bsoft,
                                                     float* __restrict__ w0,
                                                     float* __restrict__ w1) {
    int tid = threadIdx.x, lane = tid & 63, wid = tid >> 6;
    int r = blockIdx.x * 4 + wid;
    const float* vr = vis + (long)r * HDIM;
    const float* tr = tag + (long)r * HDIM;
    const float* pr = pos + (long)r * HDIM;
    int k = lane * 8;
    float s0 = 0.f, s1 = 0.f;
    #pragma unroll
    for (int j = 0; j < 8; ++j) {
        float t = vr[k + j] + tr[k + j] + pr[k + j];
        s0 += t * Wsoft[(k + j) * 2];
        s1 += t * Wsoft[(k + j) * 2 + 1];
    }
    for (int off = 32; off; off >>= 1) {
        s0 += __shfl_down(s0, off);
        s1 += __shfl_down(s1, off);
    }
    if (lane == 0) {
        float l0 = (s0 + bsoft[0]) / 0.03f;
        float l1 = (s1 + bsoft[1]) / 0.03f;
        float m = fmaxf(l0, l1);
        float lse = m + logf(expf(l0 - m) + expf(l1 - m));
        w0[r] = l0 - lse;
        w1[r] = l1 - lse;
    }
}

// ---------------------------------------------------------------- GEMM2: vis2 = [vis*w0 | tag*w1] @ [Wvp; Wtag] + bvp + btag + pos
__global__ __launch_bounds__(256) void gemm2_kernel(const float* __restrict__ vis,
                                                    const float* __restrict__ tag,
                                                    const float* __restrict__ w0,
                                                    const float* __restrict__ w1,
                                                    const float* __restrict__ Wvp,
                                                    const float* __restrict__ Wtag,
                                                    const float* __restrict__ bvp,
                                                    const float* __restrict__ btag,
                                                    const float* __restrict__ pos,
                                                    float* __restrict__ out) {
    __shared__ float As[KT][34];
    int tid = threadIdx.x;
    int bx = blockIdx.x, by = blockIdx.y;
    int ct = tid & 15, rt = tid >> 4;
    int c0 = by * 64 + ct * 4;
    int r0 = bx * 32 + rt * 2;
    int lrow = tid >> 3;
    int lk0  = (tid & 7) * 4;
    int grow = bx * 32 + lrow;
    float sw0 = w0[grow], sw1 = w1[grow];
    float acc[2][4] = {{0.f,0.f,0.f,0.f},{0.f,0.f,0.f,0.f}};
    for (int k0 = 0; k0 < 2 * HDIM; k0 += KT) {
        #pragma unroll
        for (int j = 0; j < 8; ++j) {
            int kk = lk0 + j * 32;
            int kg = k0 + kk;
            float4 v; float s;
            if (kg < HDIM) {
                v = *(const float4*)&vis[(long)grow * HDIM + kg];
                s = sw0;
            } else {
                v = *(const float4*)&tag[(long)grow * HDIM + kg - HDIM];
                s = sw1;
            }
            As[kk + 0][lrow] = v.x * s; As[kk + 1][lrow] = v.y * s;
            As[kk + 2][lrow] = v.z * s; As[kk + 3][lrow] = v.w * s;
        }
        __syncthreads();
        const float* Wb = (k0 < HDIM) ? (Wvp + (long)k0 * HDIM)
                                      : (Wtag + (long)(k0 - HDIM) * HDIM);
        #pragma unroll 8
        for (int k = 0; k < KT; ++k) {
            float4 w = *(const float4*)&Wb[(long)k * HDIM + c0];
            float2 a = *(const float2*)&As[k][2 * rt];
            acc[0][0] += a.x * w.x; acc[0][1] += a.x * w.y;
            acc[0][2] += a.x * w.z; acc[0][3] += a.x * w.w;
            acc[1][0] += a.y * w.x; acc[1][1] += a.y * w.y;
            acc[1][2] += a.y * w.z; acc[1][3] += a.y * w.w;
        }
        __syncthreads();
    }
    float4 b1 = *(const float4*)&bvp[c0];
    float4 b2 = *(const float4*)&btag[c0];
    #pragma unroll
    for (int i = 0; i < 2; ++i) {
        int r = r0 + i;
        float4 p = *(const float4*)&pos[(long)r * HDIM + c0];
        float4 o;
        o.x = acc[i][0] + b1.x + b2.x + p.x;
        o.y = acc[i][1] + b1.y + b2.y + p.y;
        o.z = acc[i][2] + b1.z + b2.z + p.z;
        o.w = acc[i][3] + b1.w + b2.w + p.w;
        *(float4*)&out[(long)r * HDIM + c0] = o;
    }
}

// ---------------------------------------------------------------- final: sim, argmax, box decode
__global__ __launch_bounds__(256) void final_kernel(const float* __restrict__ vis2,
                                                    const float* __restrict__ lnorm,
                                                    const int* __restrict__ idx,
                                                    const float* __restrict__ boxes,
                                                    float* __restrict__ out) {
    __shared__ float lns[HDIM];
    __shared__ float sims[SEL];
    int b = blockIdx.x, tid = threadIdx.x;
    int lane = tid & 63, wid = tid >> 6;
    lns[tid]       = lnorm[b * HDIM + tid];
    lns[tid + 256] = lnorm[b * HDIM + tid + 256];
    __syncthreads();
    for (int j = 0; j < 8; ++j) {
        int s = wid + j * 4;
        const float* vr = vis2 + (long)(b * SEL + s) * HDIM;
        int k = lane * 8;
        float ss = 0.f, dot = 0.f;
        #pragma unroll
        for (int t = 0; t < 8; ++t) {
            float v = vr[k + t];
            ss += v * v;
            dot += v * lns[k + t];
        }
        for (int off = 32; off; off >>= 1) {
            ss += __shfl_down(ss, off);
            dot += __shfl_down(dot, off);
        }
        if (lane == 0) {
            float sim = dot / (sqrtf(ss) + 1e-8f);
            out[BS * 5 + b * SEL + s] = sim;
            sims[s] = sim;
        }
    }
    __syncthreads();
    if (tid == 0) {
        int bsi = 0; float bvv = sims[0];
        for (int s = 1; s < SEL; ++s)
            if (sims[s] > bvv) { bvv = sims[s]; bsi = s; }
        int g = idx[b * SEL + bsi];
        const float* bb = boxes + ((long)(b * GRID_N + g)) * A_N * CH;
        float o0 = bb[4], o1 = bb[CH + 4], o2 = bb[2 * CH + 4];
        int j = 0; float ov = o0;
        if (o1 > ov) { ov = o1; j = 1; }
        if (o2 > ov) { ov = o2; j = 2; }
        const float* sb = bb + j * CH;
        float x = sb[0], y = sb[1], w = sb[2], h = sb[3];
        float x1 = x - w * 0.5f, y1 = y - h * 0.5f;
        out[b * 5 + 0] = x1;
        out[b * 5 + 1] = y1;
        out[b * 5 + 2] = x1 + w;
        out[b * 5 + 3] = y1 + h;
        out[b * 5 + 4] = sb[4];
    }
}

// ---------------------------------------------------------------- launch
extern "C" void kernel_launch(void* const* d_in, const int* in_sizes, int n_in,
                              void* d_out, int out_size, void* d_ws, size_t ws_size,
                              hipStream_t stream) {
    const float* boxes    = (const float*)d_in[0];
    const float* x_feat   = (const float*)d_in[1];
    const float* tag_emb  = (const float*)d_in[2];
    const float* pos_emb  = (const float*)d_in[3];
    const float* lang     = (const float*)d_in[4];
    const float* W_vs     = (const float*)d_in[5];
    const float* b_vs     = (const float*)d_in[6];
    const float* W_ts     = (const float*)d_in[7];
    const float* b_ts     = (const float*)d_in[8];
    const float* W_vs_pos = (const float*)d_in[9];
    const float* b_vs_pos = (const float*)d_in[10];
    const float* W_tag    = (const float*)d_in[11];
    const float* b_tag    = (const float*)d_in[12];
    const float* W_soft   = (const float*)d_in[13];
    const float* b_soft   = (const float*)d_in[14];
    float* out = (float*)d_out;

    // Workspace OOB guard: round 0's post-timing divergence is consistent with
    // ws overflow corrupting adjacent allocations. If ws is too small, do
    // nothing (constant behavior per session -> clean, diagnosable failure).
    if (ws_size < (size_t)WS_TOTAL_FLOATS * sizeof(float)) return;

    float* wsf   = (float*)d_ws;
    int*   wsidx = (int*)d_ws;             // 1024 ints at base
    float* vis   = wsf + WS_VIS;
    float* vis2  = wsf + WS_VIS2;
    float* ln    = wsf + WS_LN;
    float* w0    = wsf + WS_W0;
    float* w1    = wsf + WS_W1;

    topk_kernel<<<BS, 256, 0, stream>>>(boxes, wsidx);
    lang_kernel<<<BS, 256, 0, stream>>>(lang, W_ts, b_ts, ln);
    gemm1_kernel<<<dim3(32, 8), 256, 0, stream>>>(x_feat, wsidx, W_vs, b_vs, vis);
    logits_kernel<<<ROWS / 4, 256, 0, stream>>>(vis, tag_emb, pos_emb, W_soft, b_soft, w0, w1);
    gemm2_kernel<<<dim3(32, 8), 256, 0, stream>>>(vis, tag_emb, w0, w1, W_vs_pos, W_tag,
                                                  b_vs_pos, b_tag, pos_emb, vis2);
    final_kernel<<<BS, 256, 0, stream>>>(vis2, ln, wsidx, boxes, out);
}